// Round 12
// baseline (765.474 us; speedup 1.0000x reference)
//
#include <hip/hip_runtime.h>
#include <stdint.h>

// ---------- bf16 helpers (raw ushort representation, RNE) ----------
__device__ __forceinline__ float b2f(unsigned short s) {
    union { uint32_t u; float f; } v; v.u = ((uint32_t)s) << 16; return v.f;
}
__device__ __forceinline__ unsigned short f2b(float f) {
    union { float f; uint32_t u; } v; v.f = f;
    uint32_t r = v.u + 0x7FFFu + ((v.u >> 16) & 1u);
    return (unsigned short)(r >> 16);
}
__device__ __forceinline__ int ld_idx(const void* p, long long i, int i64) {
    return i64 ? (int)((const long long*)p)[i] : ((const int*)p)[i];
}
__device__ __forceinline__ unsigned short cvt_at(const void* p, size_t i, int f32) {
    return f32 ? f2b(((const float*)p)[i]) : ((const unsigned short*)p)[i];
}

typedef __bf16 bf16x8 __attribute__((ext_vector_type(8)));
typedef float  f32x4  __attribute__((ext_vector_type(4)));

// ---------- dtype detection: flags[0]=floats-are-f32, flags[1]=ints-are-i64 ----------
__global__ void detect_kernel(const void* __restrict__ x, const void* __restrict__ eidx,
                              int* __restrict__ flags) {
    __shared__ int cntF, cntI;
    int t = threadIdx.x;
    if (t == 0) { cntF = 0; cntI = 0; }
    __syncthreads();
    const unsigned short* xs = (const unsigned short*)x;
    int lf = 0;
    for (int i = t; i < 4096; i += 256) {
        unsigned short v = xs[2 * i];
        int e = (v >> 7) & 0xFF;
        if (v == 0 || (e >= 100 && e <= 140)) lf++;
    }
    const int* ei = (const int*)eidx;
    int li = 0;
    for (int i = t; i < 2048; i += 256)
        if (ei[2 * i + 1] != 0) li++;
    atomicAdd(&cntF, lf);
    atomicAdd(&cntI, li);
    __syncthreads();
    if (t == 0) {
        flags[0] = (cntF < 3000) ? 1 : 0;
        flags[1] = (cntI < 64) ? 1 : 0;
    }
}

// ---------- fused weight prep (r8, measured -37us with gather unroll) ----------
// Linear segmented index space; per-element logic identical to the old calls:
//   convt(W,off,Wt,K,N): Wt[n*K+k] = cvt(W[off + k*N + n])   (Wt is [N][K])
__global__ void prep_kernel(
    const void* __restrict__ fc1W, const void* __restrict__ r1w, const void* __restrict__ r1r,
    const void* __restrict__ r2w, const void* __restrict__ r2r, const void* __restrict__ fc2W,
    const void* __restrict__ fc1b, const void* __restrict__ r1b, const void* __restrict__ r2b,
    const void* __restrict__ fc2b, const void* __restrict__ outW, const void* __restrict__ outb,
    unsigned short* __restrict__ fc1t, unsigned short* __restrict__ Wcat1,
    unsigned short* __restrict__ Wcat2, unsigned short* __restrict__ fc2t,
    unsigned short* __restrict__ fc1bc, unsigned short* __restrict__ bcat1,
    unsigned short* __restrict__ bcat2, unsigned short* __restrict__ fc2bc,
    unsigned short* __restrict__ outWc, unsigned short* __restrict__ outbc,
    const int* __restrict__ flags)
{
    int f32 = flags[0];
    int id = blockIdx.x * 256 + threadIdx.x;
    // S0: fc1t
    if (id < 589824) {
        int n = id / 768, k = id - n * 768;
        fc1t[id] = cvt_at(fc1W, (size_t)k * 768 + n, f32);
        return;
    }
    id -= 589824;
    // S1-3: Wcat1
    if (id < 3 * 196608) {
        int sl = id / 196608, l = id - sl * 196608;
        int n = l / 768, k = l - n * 768;
        const void* src = (sl == 2) ? r1r : r1w;
        size_t off = (sl == 1) ? (size_t)768 * 256 : 0;
        Wcat1[id] = cvt_at(src, off + (size_t)k * 256 + n, f32);
        return;
    }
    id -= 3 * 196608;
    // S4-6: Wcat2
    if (id < 3 * 65536) {
        int sl = id / 65536, l = id - sl * 65536;
        int n = l / 256, k = l - n * 256;
        const void* src = (sl == 2) ? r2r : r2w;
        size_t off = (sl == 1) ? (size_t)65536 : 0;
        Wcat2[id] = cvt_at(src, off + (size_t)k * 256 + n, f32);
        return;
    }
    id -= 3 * 65536;
    // S7: fc2t
    if (id < 65536) {
        int n = id / 256, k = id - n * 256;
        fc2t[id] = cvt_at(fc2W, (size_t)k * 256 + n, f32);
        return;
    }
    id -= 65536;
    if (id < 768) { fc1bc[id] = cvt_at(fc1b, id, f32); return; }
    id -= 768;
    if (id < 768) { bcat1[id] = (id < 512) ? (unsigned short)0 : cvt_at(r1b, id - 512, f32); return; }
    id -= 768;
    if (id < 768) { bcat2[id] = (id < 512) ? (unsigned short)0 : cvt_at(r2b, id - 512, f32); return; }
    id -= 768;
    if (id < 256) { fc2bc[id] = cvt_at(fc2b, id, f32); return; }
    id -= 256;
    if (id < 512) { outWc[id] = cvt_at(outW, id, f32); return; }
    id -= 512;
    if (id < 2) { outbc[id] = cvt_at(outb, id, f32); }
}

// ---------- x -> bf16 bulk convert (8 elems/thread) ----------
__global__ void convx_kernel(const void* __restrict__ src, unsigned short* __restrict__ dst,
                             int n8, const int* __restrict__ flags) {
    int i = blockIdx.x * 256 + threadIdx.x;
    if (i < n8) {
        if (flags[0]) {
            const float4* p = (const float4*)src + (size_t)i * 2;
            float4 a = p[0], b = p[1];
            union { int4 v; unsigned short s[8]; } u;
            u.s[0] = f2b(a.x); u.s[1] = f2b(a.y); u.s[2] = f2b(a.z); u.s[3] = f2b(a.w);
            u.s[4] = f2b(b.x); u.s[5] = f2b(b.y); u.s[6] = f2b(b.z); u.s[7] = f2b(b.w);
            ((int4*)dst)[i] = u.v;
        } else {
            ((int4*)dst)[i] = ((const int4*)src)[i];
        }
    }
}

__global__ void zero_kernel(int* __restrict__ p, int n) {
    int i = blockIdx.x * 256 + threadIdx.x;
    if (i < n) p[i] = 0;
}

// ---------- per-(relation,dst) edge counts (flag-aware, clamped) ----------
__global__ void count_kernel(const void* __restrict__ eidx, const void* __restrict__ etype,
                             int* __restrict__ cnt, int E, int NN,
                             const int* __restrict__ flags) {
    int e = blockIdx.x * 256 + threadIdx.x;
    if (e < E) {
        int i64 = flags[1];
        int d = ld_idx(eidx, (long long)E + e, i64);
        d = min(max(d, 0), NN - 1);
        int ty = ld_idx(etype, e, i64) & 1;
        atomicAdd(&cnt[ty * NN + d], 1);
    }
}

__global__ void inv_deg_kernel(const int* __restrict__ cnt, float* __restrict__ inv,
                               int* __restrict__ deg, int NN) {
    int i = blockIdx.x * 256 + threadIdx.x;
    if (i < NN) {
        int c0 = cnt[i], c1 = cnt[NN + i];
        inv[i]      = 1.0f / (float)max(c0, 1);
        inv[NN + i] = 1.0f / (float)max(c1, 1);
        deg[i] = c0 + c1;
    }
}

// ---------- 3-phase parallel scan (round-7-proven) ----------
__global__ void blocksum_kernel(const int* __restrict__ deg, int* __restrict__ bsum, int n) {
    __shared__ int red[256];
    int t = threadIdx.x, b = blockIdx.x;
    int base = b * 1024 + t * 4;
    int s = 0;
    #pragma unroll
    for (int j = 0; j < 4; ++j) {
        int idx = base + j;
        if (idx < n) s += deg[idx];
    }
    red[t] = s;
    __syncthreads();
    for (int off = 128; off > 0; off >>= 1) {
        if (t < off) red[t] += red[t + off];
        __syncthreads();
    }
    if (t == 0) bsum[b] = red[0];
}
__global__ void scan_bsum_kernel(int* __restrict__ bsum, int nb) {
    if (threadIdx.x == 0 && blockIdx.x == 0) {
        int acc = 0;
        for (int i = 0; i < nb; ++i) { int v = bsum[i]; bsum[i] = acc; acc += v; }
    }
}
__global__ void scan_phase3(const int* __restrict__ deg, const int* __restrict__ bsum,
                            int* __restrict__ row_ptr, int* __restrict__ pos, int n) {
    __shared__ int buf[256];
    int t = threadIdx.x, b = blockIdx.x;
    int base = b * 1024;
    int v[4]; int s = 0;
    #pragma unroll
    for (int j = 0; j < 4; ++j) {
        int idx = base + t * 4 + j;
        v[j] = (idx < n) ? deg[idx] : 0;
        s += v[j];
    }
    buf[t] = s;
    __syncthreads();
    for (int off = 1; off < 256; off <<= 1) {
        int xv = (t >= off) ? buf[t - off] : 0;
        __syncthreads();
        buf[t] += xv;
        __syncthreads();
    }
    int run = buf[t] - s + bsum[b];
    #pragma unroll
    for (int j = 0; j < 4; ++j) {
        int idx = base + t * 4 + j;
        if (idx < n) {
            run += v[j];
            row_ptr[idx + 1] = run;
            if (idx + 1 < n) pos[idx + 1] = run;
        }
    }
    if (b == 0 && t == 0) { row_ptr[0] = 0; pos[0] = 0; }
}

// ---------- CSR fill: packed[slot] = (rel<<24) | src ----------
__global__ void fill_kernel(const void* __restrict__ eidx, const void* __restrict__ etype,
                            int* __restrict__ pos, int* __restrict__ packed, int E, int NN,
                            const int* __restrict__ flags) {
    int e = blockIdx.x * 256 + threadIdx.x;
    if (e < E) {
        int i64 = flags[1];
        int s = ld_idx(eidx, e, i64);
        int d = ld_idx(eidx, (long long)E + e, i64);
        s = min(max(s, 0), NN - 1);
        d = min(max(d, 0), NN - 1);
        int ty = ld_idx(etype, e, i64) & 1;
        int slot = atomicAdd(&pos[d], 1);
        packed[slot] = (ty << 24) | s;
    }
}

// ---------- MFMA bf16 GEMM (m97 structure, 128x128) -- kept for fc2 (N=256) ----------
template<bool LEAKY, bool HAS_BIAS>
__global__ __launch_bounds__(256) void gemm_kernel(
    const unsigned short* __restrict__ A,    // [MP,K] bf16 (MP = ceil128(M) valid rows)
    const unsigned short* __restrict__ Wt,   // [N,K] bf16
    const unsigned short* __restrict__ bias, // [N] bf16, or null
    unsigned short* __restrict__ C,          // [M,N] bf16
    int M, int N, int K)
{
    __shared__ __align__(16) unsigned short As[128 * 64];
    __shared__ __align__(16) unsigned short Bs[128 * 64];

    const int t    = threadIdx.x;
    const int lane = t & 63;
    const int wave = t >> 6;
    const int wm   = wave >> 1;
    const int wn   = wave & 1;
    const int l16  = lane & 15;
    const int quad = lane >> 4;
    const int col0 = blockIdx.x * 128;
    const int row0 = blockIdx.y * 128;
    const int srow = wave * 8 + (lane >> 3);
    const int scol = (lane & 7) * 8;

    f32x4 acc[4][4] = {};

    for (int k0 = 0; k0 < K; k0 += 64) {
        #pragma unroll
        for (int j = 0; j < 4; ++j) {
            __builtin_amdgcn_global_load_lds(
                (const __attribute__((address_space(1))) unsigned int*)
                    (A + (size_t)(row0 + j * 32 + srow) * K + k0 + scol),
                (__attribute__((address_space(3))) unsigned int*)
                    (&As[(j * 32 + wave * 8) * 64]),
                16, 0, 0);
            __builtin_amdgcn_global_load_lds(
                (const __attribute__((address_space(1))) unsigned int*)
                    (Wt + (size_t)(col0 + j * 32 + srow) * K + k0 + scol),
                (__attribute__((address_space(3))) unsigned int*)
                    (&Bs[(j * 32 + wave * 8) * 64]),
                16, 0, 0);
        }
        __syncthreads();

        #pragma unroll
        for (int kk = 0; kk < 2; ++kk) {
            bf16x8 af[4], bfr[4];
            #pragma unroll
            for (int mi = 0; mi < 4; ++mi)
                af[mi] = *reinterpret_cast<const bf16x8*>(
                    &As[(wm * 64 + mi * 16 + l16) * 64 + kk * 32 + quad * 8]);
            #pragma unroll
            for (int ni = 0; ni < 4; ++ni)
                bfr[ni] = *reinterpret_cast<const bf16x8*>(
                    &Bs[(wn * 64 + ni * 16 + l16) * 64 + kk * 32 + quad * 8]);
            #pragma unroll
            for (int mi = 0; mi < 4; ++mi)
                #pragma unroll
                for (int ni = 0; ni < 4; ++ni)
                    acc[mi][ni] = __builtin_amdgcn_mfma_f32_16x16x32_bf16(
                        af[mi], bfr[ni], acc[mi][ni], 0, 0, 0);
        }
        __syncthreads();
    }

    #pragma unroll
    for (int mi = 0; mi < 4; ++mi) {
        #pragma unroll
        for (int ni = 0; ni < 4; ++ni) {
            int ccol = col0 + wn * 64 + ni * 16 + l16;
            float bv = HAS_BIAS ? b2f(bias[ccol]) : 0.0f;
            #pragma unroll
            for (int i = 0; i < 4; ++i) {
                int r = row0 + wm * 64 + mi * 16 + quad * 4 + i;
                if (r < M) {
                    float v = acc[mi][ni][i] + bv;
                    if (LEAKY) v = (v >= 0.0f) ? v : 0.01f * v;
                    C[(size_t)r * N + ccol] = f2b(v);
                }
            }
        }
    }
}

// ---------- 256x256 16-wave 4-phase MFMA GEMM (r11: drop lgkm-drain pinning) ----------
// r7/r11 control measured 101.4+-0.2us (noise <0.5%), MfmaUtil 23.5, phases
// ~4000cyc vs ~310cyc MFMA need. r11 theory: the explicit
// `lgkmcnt(0)+sched_barrier(0)` before the MFMA cluster pinned ALL 8
// ds_read_b128 to drain before ANY MFMA -- a per-phase serialization the
// compiler would otherwise avoid with fine-grained lgkmcnt(4/3/1/0)
// interleave (m97 finding; rule #18 applies to inline-asm ds_reads only,
// ours are IR-level). This edit removes ONLY that pair. WAR safety: every
// loaded frag feeds an MFMA before the end-of-phase barrier, so compiler
// waits retire all reads before the wave crosses it; numerics unchanged
// (per-acc chains are sequential dependencies).
// Ledger unchanged: stages P1:b1.kk1, P2:b0'.kk0, P3:b0'.kk1, P4:b1'.kk0;
// uniform vmcnt(4)/phase; prologue 6 loads vmcnt(4); tail 4/2/0/none.
template<bool LEAKY>
__global__ __launch_bounds__(1024, 4) void gemm256_kernel(
    const unsigned short* __restrict__ A,    // [MP,K] bf16 (MP = ceil256(M) readable rows)
    const unsigned short* __restrict__ Wt,   // [N,K] bf16
    const unsigned short* __restrict__ bias, // [N] bf16
    unsigned short* __restrict__ C,          // [M,N] bf16
    int M, int N, int K)                     // K multiple of 128, K>=256
{
    __shared__ __align__(16) unsigned short lds[65536];   // 128 KiB

    const int t    = threadIdx.x;
    const int lane = t & 63;
    const int wave = t >> 6;       // 0..15
    const int wm   = wave >> 2;    // 0..3  (M quarter, 64 rows)
    const int wn   = wave & 3;     // 0..3  (N quarter, 64 cols)
    const int l16  = lane & 15;
    const int q    = lane >> 4;    // 0..3

    int gx   = gridDim.x;
    int nwg  = gx * gridDim.y;
    int flat = blockIdx.y * gx + blockIdx.x;
    int qq = nwg >> 3, rr = nwg & 7;
    int xcd = flat & 7, idx = flat >> 3;
    int nf = (xcd < rr ? xcd * (qq + 1) : rr * (qq + 1) + (xcd - rr) * qq) + idx;
    const int col0 = (nf % gx) * 256;
    const int row0 = (nf / gx) * 256;

    const int srow = lane >> 2;                               // row in block
    const int scol = 8 * ((lane & 3) ^ ((lane >> 3) & 3));    // ushort col, pre-swizzled
    const int roff = l16 * 32 + 8 * (q ^ ((l16 >> 1) & 3));

    f32x4 acc[4][4] = {};

#define STAGE2(buf, kh, tile)                                                  \
    do {                                                                       \
        __builtin_amdgcn_global_load_lds(                                      \
            (const __attribute__((address_space(1))) unsigned int*)            \
                (A + (size_t)(row0 + wave * 16 + srow) * K                     \
                   + (tile) * 64 + (kh) * 32 + scol),                          \
            (__attribute__((address_space(3))) unsigned int*)                  \
                (&lds[(buf) * 32768 + wave * 1024 + (kh) * 512]),              \
            16, 0, 0);                                                         \
        __builtin_amdgcn_global_load_lds(                                      \
            (const __attribute__((address_space(1))) unsigned int*)            \
                (Wt + (size_t)(col0 + wave * 16 + srow) * K                    \
                    + (tile) * 64 + (kh) * 32 + scol),                         \
            (__attribute__((address_space(3))) unsigned int*)                  \
                (&lds[(buf) * 32768 + 16384 + wave * 1024 + (kh) * 512]),      \
            16, 0, 0);                                                         \
    } while (0)

#define PHASE(buf, kk, STAGE_STMT, WAIT_STMT)                                  \
    do {                                                                       \
        bf16x8 af_[4], bf_[4];                                                 \
        _Pragma("unroll")                                                      \
        for (int m2 = 0; m2 < 4; ++m2)                                         \
            af_[m2] = *reinterpret_cast<const bf16x8*>(                        \
                &lds[(buf) * 32768 + (wm * 4 + m2) * 1024                      \
                     + (kk) * 512 + roff]);                                    \
        _Pragma("unroll")                                                      \
        for (int n2 = 0; n2 < 4; ++n2)                                         \
            bf_[n2] = *reinterpret_cast<const bf16x8*>(                        \
                &lds[(buf) * 32768 + 16384 + (wn * 4 + n2) * 1024              \
                     + (kk) * 512 + roff]);                                    \
        STAGE_STMT;                                                            \
        __builtin_amdgcn_s_barrier();                                          \
        __builtin_amdgcn_s_setprio(1);                                         \
        _Pragma("unroll")                                                      \
        for (int m2 = 0; m2 < 4; ++m2)                                         \
            _Pragma("unroll")                                                  \
            for (int n2 = 0; n2 < 4; ++n2)                                     \
                acc[m2][n2] = __builtin_amdgcn_mfma_f32_16x16x32_bf16(         \
                    af_[m2], bf_[n2], acc[m2][n2], 0, 0, 0);                   \
        __builtin_amdgcn_s_setprio(0);                                         \
        WAIT_STMT;                                                             \
        __builtin_amdgcn_s_barrier();                                          \
    } while (0)

    STAGE2(0, 0, 0);
    STAGE2(0, 1, 0);
    STAGE2(1, 0, 1);
    asm volatile("s_waitcnt vmcnt(4)" ::: "memory");
    __builtin_amdgcn_s_barrier();

    const int nIter = K >> 7;   // K/128, >=2 for all call sites (K=768,256)
    for (int i = 0; i < nIter - 1; ++i) {
        const int T0 = 2 * i, T1 = 2 * i + 1;
        PHASE(0, 0, STAGE2(1, 1, T1),
              asm volatile("s_waitcnt vmcnt(4)" ::: "memory"));                 // P1
        PHASE(0, 1, STAGE2(0, 0, T0 + 2),
              asm volatile("s_waitcnt vmcnt(4)" ::: "memory"));                 // P2
        PHASE(1, 0, STAGE2(0, 1, T0 + 2),
              asm volatile("s_waitcnt vmcnt(4)" ::: "memory"));                 // P3
        PHASE(1, 1, STAGE2(1, 0, T1 + 2),
              asm volatile("s_waitcnt vmcnt(4)" ::: "memory"));                 // P4
    }
    {
        const int T1 = 2 * nIter - 1;
        PHASE(0, 0, STAGE2(1, 1, T1),
              asm volatile("s_waitcnt vmcnt(4)" ::: "memory"));
        PHASE(0, 1, , asm volatile("s_waitcnt vmcnt(2)" ::: "memory"));
        PHASE(1, 0, , asm volatile("s_waitcnt vmcnt(0)" ::: "memory"));
        PHASE(1, 1, , );
    }
#undef PHASE
#undef STAGE2

    // epilogue: C/D mapping col=lane&15, row=quad*4+j  [m89/m91]
    #pragma unroll
    for (int mi = 0; mi < 4; ++mi) {
        #pragma unroll
        for (int ni = 0; ni < 4; ++ni) {
            int ccol = col0 + wn * 64 + ni * 16 + l16;
            float bv = b2f(bias[ccol]);
            #pragma unroll
            for (int j = 0; j < 4; ++j) {
                int r = row0 + wm * 64 + mi * 16 + q * 4 + j;
                if (r < M) {
                    float v = acc[mi][ni][j] + bv;
                    if (LEAKY) v = (v >= 0.0f) ? v : 0.01f * v;
                    C[(size_t)r * N + ccol] = f2b(v);
                }
            }
        }
    }
}

// ---------- CSR gather over fused layer buffer P[*,768], 2-edge unrolled (r8) ----------
__global__ __launch_bounds__(256) void gather_kernel(
    const int* __restrict__ row_ptr, const int* __restrict__ packed,
    const float* __restrict__ inv,
    const unsigned short* __restrict__ P,     // [*,768] bf16
    unsigned short* __restrict__ outp,        // [*,256] bf16
    int NN)
{
    int i    = blockIdx.x * 4 + (threadIdx.x >> 6);
    int lane = threadIdx.x & 63;
    int q    = lane >> 4;
    int l16  = lane & 15;
    if (i >= NN) return;
    float w0 = inv[i], w1 = inv[NN + i];
    float a[16] = {};
    if (q == 0) {
        const int4* rp = (const int4*)(P + (size_t)i * 768 + 512 + l16 * 16);
        union { int4 v; unsigned short s[8]; } r0u, r1u;
        r0u.v = rp[0]; r1u.v = rp[1];
        #pragma unroll
        for (int j = 0; j < 8; ++j) { a[j] = b2f(r0u.s[j]); a[8 + j] = b2f(r1u.s[j]); }
    }
    int e  = row_ptr[i] + q;
    int e1 = row_ptr[i + 1];
    for (; e + 4 < e1; e += 8) {
        int pA = packed[e];
        int pB = packed[e + 4];
        int sA = pA & 0xFFFFFF; if (sA >= NN) sA = NN - 1;
        int sB = pB & 0xFFFFFF; if (sB >= NN) sB = NN - 1;
        int rA = (pA >> 24) & 1;
        int rB = (pB >> 24) & 1;
        float wA = rA ? w1 : w0;
        float wB = rB ? w1 : w0;
        const int4* hpA = (const int4*)(P + (size_t)sA * 768 + rA * 256 + l16 * 16);
        const int4* hpB = (const int4*)(P + (size_t)sB * 768 + rB * 256 + l16 * 16);
        union { int4 v; unsigned short s8[8]; } a0, a1, b0, b1;
        a0.v = hpA[0]; a1.v = hpA[1];
        b0.v = hpB[0]; b1.v = hpB[1];
        #pragma unroll
        for (int j = 0; j < 8; ++j) {
            a[j]     += wA * b2f(a0.s8[j]);
            a[8 + j] += wA * b2f(a1.s8[j]);
        }
        #pragma unroll
        for (int j = 0; j < 8; ++j) {
            a[j]     += wB * b2f(b0.s8[j]);
            a[8 + j] += wB * b2f(b1.s8[j]);
        }
    }
    if (e < e1) {
        int p = packed[e];
        int s = p & 0xFFFFFF;
        if (s >= NN) s = NN - 1;
        int r = (p >> 24) & 1;
        float w = r ? w1 : w0;
        const int4* hp = (const int4*)(P + (size_t)s * 768 + r * 256 + l16 * 16);
        union { int4 v; unsigned short s8[8]; } h0, h1;
        h0.v = hp[0]; h1.v = hp[1];
        #pragma unroll
        for (int j = 0; j < 8; ++j) {
            a[j]     += w * b2f(h0.s8[j]);
            a[8 + j] += w * b2f(h1.s8[j]);
        }
    }
    #pragma unroll
    for (int j = 0; j < 16; ++j) {
        a[j] += __shfl_down(a[j], 32);
        a[j] += __shfl_down(a[j], 16);
    }
    if (q == 0) {
        union { int4 v; unsigned short s[8]; } o0, o1;
        #pragma unroll
        for (int j = 0; j < 8; ++j) { o0.s[j] = f2b(a[j]); o1.s[j] = f2b(a[8 + j]); }
        int4* op = (int4*)(outp + (size_t)i * 256 + l16 * 16);
        op[0] = o0.v;
        op[1] = o1.v;
    }
}

// ---------- head: softmax(h@outW + outb) over 2 classes; flag-aware store ----------
__global__ __launch_bounds__(256) void head_kernel(
    const unsigned short* __restrict__ h,
    const unsigned short* __restrict__ outW,   // [256,2] bf16 (converted)
    const unsigned short* __restrict__ outb,   // [2] bf16 (converted)
    void* __restrict__ out, int M, const int* __restrict__ flags)
{
    int row  = blockIdx.x * 4 + (threadIdx.x >> 6);
    int lane = threadIdx.x & 63;
    if (row >= M) return;
    ushort4 hv = *reinterpret_cast<const ushort4*>(h + (size_t)row * 256 + lane * 4);
    union { int4 v; unsigned short s[8]; } wu;
    wu.v = *reinterpret_cast<const int4*>(outW + lane * 8);
    float hf[4] = { b2f(hv.x), b2f(hv.y), b2f(hv.z), b2f(hv.w) };
    float s0 = 0.0f, s1 = 0.0f;
    #pragma unroll
    for (int i = 0; i < 4; ++i) {
        s0 += hf[i] * b2f(wu.s[2 * i]);
        s1 += hf[i] * b2f(wu.s[2 * i + 1]);
    }
    #pragma unroll
    for (int off2 = 32; off2 >= 1; off2 >>= 1) {
        s0 += __shfl_down(s0, off2);
        s1 += __shfl_down(s1, off2);
    }
    if (lane == 0) {
        s0 += b2f(outb[0]); s1 += b2f(outb[1]);
        float m  = fmaxf(s0, s1);
        float e0 = expf(s0 - m), e1 = expf(s1 - m);
        float is = 1.0f / (e0 + e1);
        if (flags[0]) {
            ((float*)out)[(size_t)row * 2 + 0] = e0 * is;
            ((float*)out)[(size_t)row * 2 + 1] = e1 * is;
        } else {
            ((unsigned short*)out)[(size_t)row * 2 + 0] = f2b(e0 * is);
            ((unsigned short*)out)[(size_t)row * 2 + 1] = f2b(e1 * is);
        }
    }
}

__global__ void diag_kernel(unsigned short* __restrict__ out, int n, float v) {
    int i = blockIdx.x * 256 + threadIdx.x;
    if (i < n) out[i] = f2b(v);
}

template<bool LEAKY, bool HAS_BIAS>
static void launch_gemm(const unsigned short* A, const unsigned short* Wt,
                        const unsigned short* bias, unsigned short* C,
                        int M, int N, int K, hipStream_t s) {
    int MP = (M + 127) & ~127;
    dim3 grid(N / 128, MP / 128);
    gemm_kernel<LEAKY, HAS_BIAS><<<grid, 256, 0, s>>>(A, Wt, bias, C, M, N, K);
}

template<bool LEAKY>
static void launch_gemm256(const unsigned short* A, const unsigned short* Wt,
                           const unsigned short* bias, unsigned short* C,
                           int M, int N, int K, hipStream_t s) {
    int MP = (M + 255) & ~255;
    dim3 grid(N / 256, MP / 256);
    gemm256_kernel<LEAKY><<<grid, 1024, 0, s>>>(A, Wt, bias, C, M, N, K);
}

extern "C" void kernel_launch(void* const* d_in, const int* in_sizes, int n_in,
                              void* d_out, int out_size, void* d_ws, size_t ws_size,
                              hipStream_t stream) {
    const int IN = 768, HID = 256;
    const int NN = in_sizes[0] / IN;        // 50000
    const int E  = in_sizes[3];             // 800000
    const int MPA = (NN + 255) & ~255;      // 50176 (256-tile padded rows)
    const int NB = (NN + 1023) / 1024;
    (void)n_in;

    const void* x    = d_in[0];
    const void* eidx = d_in[1];
    const void* etyp = d_in[3];
    const void* fc1W = d_in[4];
    const void* fc1b = d_in[5];
    const void* r1w  = d_in[6];
    const void* r1r  = d_in[7];
    const void* r1b  = d_in[8];
    const void* r2w  = d_in[9];
    const void* r2r  = d_in[10];
    const void* r2b  = d_in[11];
    const void* fc2W = d_in[12];
    const void* fc2b = d_in[13];
    const void* outW = d_in[14];
    const void* outb = d_in[15];

    // ---- workspace carve (~163 MB total; 187 MB proven available) ----
    char* ws = (char*)d_ws;
    size_t off = 0;
    auto carve = [&](size_t bytes) {
        char* p = ws + off; off += (bytes + 255) & ~(size_t)255; return p;
    };
    int*   flags = (int*)carve(64);
    unsigned short* fc1t  = (unsigned short*)carve((size_t)IN * IN * 2);
    unsigned short* Wcat1 = (unsigned short*)carve((size_t)IN * IN * 2);
    unsigned short* Wcat2 = (unsigned short*)carve((size_t)IN * HID * 2);
    unsigned short* fc2t  = (unsigned short*)carve((size_t)HID * HID * 2);
    unsigned short* fc1bc = (unsigned short*)carve((size_t)IN * 2);
    unsigned short* bcat1 = (unsigned short*)carve((size_t)IN * 2);
    unsigned short* bcat2 = (unsigned short*)carve((size_t)IN * 2);
    unsigned short* fc2bc = (unsigned short*)carve((size_t)HID * 2);
    unsigned short* outWc = (unsigned short*)carve((size_t)HID * 2 * 2);
    unsigned short* outbc = (unsigned short*)carve(2 * 2);
    int*   icnt    = (int*)carve((size_t)2 * NN * 4);
    float* inv     = (float*)carve((size_t)2 * NN * 4);
    int*   deg     = (int*)carve((size_t)NN * 4);
    int*   row_ptr = (int*)carve((size_t)(NN + 1) * 4);
    int*   pos     = (int*)carve((size_t)NN * 4);
    int*   bsum    = (int*)carve(256 * 4);
    int*   packed  = (int*)carve((size_t)E * 4);
    unsigned short* RA = (unsigned short*)carve((size_t)MPA * IN * 2);  // 77.1 MB
    unsigned short* RB = (unsigned short*)carve((size_t)MPA * IN * 2);  // 77.1 MB

    auto tg = [](int n) { return (n + 255) / 256; };

    if (ws_size < off) {
        float v = fminf((float)(ws_size >> 20), 300.0f) / 1000.0f;
        diag_kernel<<<tg(out_size), 256, 0, stream>>>((unsigned short*)d_out, out_size, v);
        return;
    }

    // ---- dtype detection ----
    detect_kernel<<<1, 256, 0, stream>>>(x, eidx, flags);

    // ---- fused weight prep (replaces 15 small dispatches) ----
    const int PREP_TOT = 589824 + 3 * 196608 + 3 * 65536 + 65536 + 768 * 3 + 256 + 512 + 2;
    prep_kernel<<<tg(PREP_TOT), 256, 0, stream>>>(
        fc1W, r1w, r1r, r2w, r2r, fc2W, fc1b, r1b, r2b, fc2b, outW, outb,
        fc1t, Wcat1, Wcat2, fc2t, fc1bc, bcat1, bcat2, fc2bc, outWc, outbc, flags);

    // ---- CSR build ----
    zero_kernel<<<tg(2 * NN), 256, 0, stream>>>(icnt, 2 * NN);
    count_kernel<<<tg(E), 256, 0, stream>>>(eidx, etyp, icnt, E, NN, flags);
    inv_deg_kernel<<<tg(NN), 256, 0, stream>>>(icnt, inv, deg, NN);
    blocksum_kernel<<<NB, 256, 0, stream>>>(deg, bsum, NN);
    scan_bsum_kernel<<<1, 64, 0, stream>>>(bsum, NB);
    scan_phase3<<<NB, 256, 0, stream>>>(deg, bsum, row_ptr, pos, NN);
    fill_kernel<<<tg(E), 256, 0, stream>>>(eidx, etyp, pos, packed, E, NN, flags);

    // ---- x -> bf16 (RA) ----
    convx_kernel<<<tg(NN * IN / 8), 256, 0, stream>>>(x, RA, NN * IN / 8, flags);

    // ---- fc1 + leakyrelu: XB(RA) -> H1(RB)  [256sq 16-wave 4-phase] ----
    launch_gemm256<true>(RA, fc1t, fc1bc, RB, NN, IN, IN, stream);

    // ---- layer 1 (fused): H1(RB) @ Wcat1 -> P1(RA) ; gather -> ACC1(RB head) ----
    launch_gemm256<false>(RB, Wcat1, bcat1, RA, NN, IN, IN, stream);
    gather_kernel<<<(NN + 3) / 4, 256, 0, stream>>>(row_ptr, packed, inv, RA, RB, NN);

    // ---- layer 2 (fused): ACC1(RB) @ Wcat2 -> P2(RA) ; gather -> ACC2(RB head) ----
    launch_gemm256<false>(RB, Wcat2, bcat2, RA, NN, IN, HID, stream);
    gather_kernel<<<(NN + 3) / 4, 256, 0, stream>>>(row_ptr, packed, inv, RA, RB, NN);

    // ---- fc2 + leakyrelu: ACC2(RB) -> H4(RA head) ; softmax head (128-tile: N=256) ----
    launch_gemm<true, true>(RB, fc2t, fc2bc, RA, NN, HID, HID, stream);
    head_kernel<<<(NN + 3) / 4, 256, 0, stream>>>(RA, outWc, outbc, d_out, NN, flags);
}

// Round 13
// 759.392 us; speedup vs baseline: 1.0080x; 1.0080x over previous
//
#include <hip/hip_runtime.h>
#include <stdint.h>

// ---------- bf16 helpers (raw ushort representation, RNE) ----------
__device__ __forceinline__ float b2f(unsigned short s) {
    union { uint32_t u; float f; } v; v.u = ((uint32_t)s) << 16; return v.f;
}
__device__ __forceinline__ unsigned short f2b(float f) {
    union { float f; uint32_t u; } v; v.f = f;
    uint32_t r = v.u + 0x7FFFu + ((v.u >> 16) & 1u);
    return (unsigned short)(r >> 16);
}
__device__ __forceinline__ int ld_idx(const void* p, long long i, int i64) {
    return i64 ? (int)((const long long*)p)[i] : ((const int*)p)[i];
}
__device__ __forceinline__ unsigned short cvt_at(const void* p, size_t i, int f32) {
    return f32 ? f2b(((const float*)p)[i]) : ((const unsigned short*)p)[i];
}

typedef __bf16 bf16x8 __attribute__((ext_vector_type(8)));
typedef float  f32x4  __attribute__((ext_vector_type(4)));

// ---------- dtype detection: flags[0]=floats-are-f32, flags[1]=ints-are-i64 ----------
__global__ void detect_kernel(const void* __restrict__ x, const void* __restrict__ eidx,
                              int* __restrict__ flags) {
    __shared__ int cntF, cntI;
    int t = threadIdx.x;
    if (t == 0) { cntF = 0; cntI = 0; }
    __syncthreads();
    const unsigned short* xs = (const unsigned short*)x;
    int lf = 0;
    for (int i = t; i < 4096; i += 256) {
        unsigned short v = xs[2 * i];
        int e = (v >> 7) & 0xFF;
        if (v == 0 || (e >= 100 && e <= 140)) lf++;
    }
    const int* ei = (const int*)eidx;
    int li = 0;
    for (int i = t; i < 2048; i += 256)
        if (ei[2 * i + 1] != 0) li++;
    atomicAdd(&cntF, lf);
    atomicAdd(&cntI, li);
    __syncthreads();
    if (t == 0) {
        flags[0] = (cntF < 3000) ? 1 : 0;
        flags[1] = (cntI < 64) ? 1 : 0;
    }
}

// ---------- fused weight prep (r8-proven, part of the -37us step) ----------
__global__ void prep_kernel(
    const void* __restrict__ fc1W, const void* __restrict__ r1w, const void* __restrict__ r1r,
    const void* __restrict__ r2w, const void* __restrict__ r2r, const void* __restrict__ fc2W,
    const void* __restrict__ fc1b, const void* __restrict__ r1b, const void* __restrict__ r2b,
    const void* __restrict__ fc2b, const void* __restrict__ outW, const void* __restrict__ outb,
    unsigned short* __restrict__ fc1t, unsigned short* __restrict__ Wcat1,
    unsigned short* __restrict__ Wcat2, unsigned short* __restrict__ fc2t,
    unsigned short* __restrict__ fc1bc, unsigned short* __restrict__ bcat1,
    unsigned short* __restrict__ bcat2, unsigned short* __restrict__ fc2bc,
    unsigned short* __restrict__ outWc, unsigned short* __restrict__ outbc,
    const int* __restrict__ flags)
{
    int f32 = flags[0];
    int id = blockIdx.x * 256 + threadIdx.x;
    // S0: fc1t
    if (id < 589824) {
        int n = id / 768, k = id - n * 768;
        fc1t[id] = cvt_at(fc1W, (size_t)k * 768 + n, f32);
        return;
    }
    id -= 589824;
    // S1-3: Wcat1
    if (id < 3 * 196608) {
        int sl = id / 196608, l = id - sl * 196608;
        int n = l / 768, k = l - n * 768;
        const void* src = (sl == 2) ? r1r : r1w;
        size_t off = (sl == 1) ? (size_t)768 * 256 : 0;
        Wcat1[id] = cvt_at(src, off + (size_t)k * 256 + n, f32);
        return;
    }
    id -= 3 * 196608;
    // S4-6: Wcat2
    if (id < 3 * 65536) {
        int sl = id / 65536, l = id - sl * 65536;
        int n = l / 256, k = l - n * 256;
        const void* src = (sl == 2) ? r2r : r2w;
        size_t off = (sl == 1) ? (size_t)65536 : 0;
        Wcat2[id] = cvt_at(src, off + (size_t)k * 256 + n, f32);
        return;
    }
    id -= 3 * 65536;
    // S7: fc2t
    if (id < 65536) {
        int n = id / 256, k = id - n * 256;
        fc2t[id] = cvt_at(fc2W, (size_t)k * 256 + n, f32);
        return;
    }
    id -= 65536;
    if (id < 768) { fc1bc[id] = cvt_at(fc1b, id, f32); return; }
    id -= 768;
    if (id < 768) { bcat1[id] = (id < 512) ? (unsigned short)0 : cvt_at(r1b, id - 512, f32); return; }
    id -= 768;
    if (id < 768) { bcat2[id] = (id < 512) ? (unsigned short)0 : cvt_at(r2b, id - 512, f32); return; }
    id -= 768;
    if (id < 256) { fc2bc[id] = cvt_at(fc2b, id, f32); return; }
    id -= 256;
    if (id < 512) { outWc[id] = cvt_at(outW, id, f32); return; }
    id -= 512;
    if (id < 2) { outbc[id] = cvt_at(outb, id, f32); }
}

// ---------- x -> bf16 bulk convert (8 elems/thread) ----------
__global__ void convx_kernel(const void* __restrict__ src, unsigned short* __restrict__ dst,
                             int n8, const int* __restrict__ flags) {
    int i = blockIdx.x * 256 + threadIdx.x;
    if (i < n8) {
        if (flags[0]) {
            const float4* p = (const float4*)src + (size_t)i * 2;
            float4 a = p[0], b = p[1];
            union { int4 v; unsigned short s[8]; } u;
            u.s[0] = f2b(a.x); u.s[1] = f2b(a.y); u.s[2] = f2b(a.z); u.s[3] = f2b(a.w);
            u.s[4] = f2b(b.x); u.s[5] = f2b(b.y); u.s[6] = f2b(b.z); u.s[7] = f2b(b.w);
            ((int4*)dst)[i] = u.v;
        } else {
            ((int4*)dst)[i] = ((const int4*)src)[i];
        }
    }
}

__global__ void zero_kernel(int* __restrict__ p, int n) {
    int i = blockIdx.x * 256 + threadIdx.x;
    if (i < n) p[i] = 0;
}

// ---------- per-(relation,dst) edge counts (flag-aware, clamped) ----------
__global__ void count_kernel(const void* __restrict__ eidx, const void* __restrict__ etype,
                             int* __restrict__ cnt, int E, int NN,
                             const int* __restrict__ flags) {
    int e = blockIdx.x * 256 + threadIdx.x;
    if (e < E) {
        int i64 = flags[1];
        int d = ld_idx(eidx, (long long)E + e, i64);
        d = min(max(d, 0), NN - 1);
        int ty = ld_idx(etype, e, i64) & 1;
        atomicAdd(&cnt[ty * NN + d], 1);
    }
}

__global__ void inv_deg_kernel(const int* __restrict__ cnt, float* __restrict__ inv,
                               int* __restrict__ deg, int NN) {
    int i = blockIdx.x * 256 + threadIdx.x;
    if (i < NN) {
        int c0 = cnt[i], c1 = cnt[NN + i];
        inv[i]      = 1.0f / (float)max(c0, 1);
        inv[NN + i] = 1.0f / (float)max(c1, 1);
        deg[i] = c0 + c1;
    }
}

// ---------- 3-phase parallel scan (round-7-proven) ----------
__global__ void blocksum_kernel(const int* __restrict__ deg, int* __restrict__ bsum, int n) {
    __shared__ int red[256];
    int t = threadIdx.x, b = blockIdx.x;
    int base = b * 1024 + t * 4;
    int s = 0;
    #pragma unroll
    for (int j = 0; j < 4; ++j) {
        int idx = base + j;
        if (idx < n) s += deg[idx];
    }
    red[t] = s;
    __syncthreads();
    for (int off = 128; off > 0; off >>= 1) {
        if (t < off) red[t] += red[t + off];
        __syncthreads();
    }
    if (t == 0) bsum[b] = red[0];
}
__global__ void scan_bsum_kernel(int* __restrict__ bsum, int nb) {
    if (threadIdx.x == 0 && blockIdx.x == 0) {
        int acc = 0;
        for (int i = 0; i < nb; ++i) { int v = bsum[i]; bsum[i] = acc; acc += v; }
    }
}
__global__ void scan_phase3(const int* __restrict__ deg, const int* __restrict__ bsum,
                            int* __restrict__ row_ptr, int* __restrict__ pos, int n) {
    __shared__ int buf[256];
    int t = threadIdx.x, b = blockIdx.x;
    int base = b * 1024;
    int v[4]; int s = 0;
    #pragma unroll
    for (int j = 0; j < 4; ++j) {
        int idx = base + t * 4 + j;
        v[j] = (idx < n) ? deg[idx] : 0;
        s += v[j];
    }
    buf[t] = s;
    __syncthreads();
    for (int off = 1; off < 256; off <<= 1) {
        int xv = (t >= off) ? buf[t - off] : 0;
        __syncthreads();
        buf[t] += xv;
        __syncthreads();
    }
    int run = buf[t] - s + bsum[b];
    #pragma unroll
    for (int j = 0; j < 4; ++j) {
        int idx = base + t * 4 + j;
        if (idx < n) {
            run += v[j];
            row_ptr[idx + 1] = run;
            if (idx + 1 < n) pos[idx + 1] = run;
        }
    }
    if (b == 0 && t == 0) { row_ptr[0] = 0; pos[0] = 0; }
}

// ---------- CSR fill: packed[slot] = (rel<<24) | src ----------
__global__ void fill_kernel(const void* __restrict__ eidx, const void* __restrict__ etype,
                            int* __restrict__ pos, int* __restrict__ packed, int E, int NN,
                            const int* __restrict__ flags) {
    int e = blockIdx.x * 256 + threadIdx.x;
    if (e < E) {
        int i64 = flags[1];
        int s = ld_idx(eidx, e, i64);
        int d = ld_idx(eidx, (long long)E + e, i64);
        s = min(max(s, 0), NN - 1);
        d = min(max(d, 0), NN - 1);
        int ty = ld_idx(etype, e, i64) & 1;
        int slot = atomicAdd(&pos[d], 1);
        packed[slot] = (ty << 24) | s;
    }
}

// ---------- MFMA bf16 GEMM (m97 structure, 128x128) -- kept for fc2 (N=256) ----------
template<bool LEAKY, bool HAS_BIAS>
__global__ __launch_bounds__(256) void gemm_kernel(
    const unsigned short* __restrict__ A,    // [MP,K] bf16 (MP = ceil128(M) valid rows)
    const unsigned short* __restrict__ Wt,   // [N,K] bf16
    const unsigned short* __restrict__ bias, // [N] bf16, or null
    unsigned short* __restrict__ C,          // [M,N] bf16
    int M, int N, int K)
{
    __shared__ __align__(16) unsigned short As[128 * 64];
    __shared__ __align__(16) unsigned short Bs[128 * 64];

    const int t    = threadIdx.x;
    const int lane = t & 63;
    const int wave = t >> 6;
    const int wm   = wave >> 1;
    const int wn   = wave & 1;
    const int l16  = lane & 15;
    const int quad = lane >> 4;
    const int col0 = blockIdx.x * 128;
    const int row0 = blockIdx.y * 128;
    const int srow = wave * 8 + (lane >> 3);
    const int scol = (lane & 7) * 8;

    f32x4 acc[4][4] = {};

    for (int k0 = 0; k0 < K; k0 += 64) {
        #pragma unroll
        for (int j = 0; j < 4; ++j) {
            __builtin_amdgcn_global_load_lds(
                (const __attribute__((address_space(1))) unsigned int*)
                    (A + (size_t)(row0 + j * 32 + srow) * K + k0 + scol),
                (__attribute__((address_space(3))) unsigned int*)
                    (&As[(j * 32 + wave * 8) * 64]),
                16, 0, 0);
            __builtin_amdgcn_global_load_lds(
                (const __attribute__((address_space(1))) unsigned int*)
                    (Wt + (size_t)(col0 + j * 32 + srow) * K + k0 + scol),
                (__attribute__((address_space(3))) unsigned int*)
                    (&Bs[(j * 32 + wave * 8) * 64]),
                16, 0, 0);
        }
        __syncthreads();

        #pragma unroll
        for (int kk = 0; kk < 2; ++kk) {
            bf16x8 af[4], bfr[4];
            #pragma unroll
            for (int mi = 0; mi < 4; ++mi)
                af[mi] = *reinterpret_cast<const bf16x8*>(
                    &As[(wm * 64 + mi * 16 + l16) * 64 + kk * 32 + quad * 8]);
            #pragma unroll
            for (int ni = 0; ni < 4; ++ni)
                bfr[ni] = *reinterpret_cast<const bf16x8*>(
                    &Bs[(wn * 64 + ni * 16 + l16) * 64 + kk * 32 + quad * 8]);
            #pragma unroll
            for (int mi = 0; mi < 4; ++mi)
                #pragma unroll
                for (int ni = 0; ni < 4; ++ni)
                    acc[mi][ni] = __builtin_amdgcn_mfma_f32_16x16x32_bf16(
                        af[mi], bfr[ni], acc[mi][ni], 0, 0, 0);
        }
        __syncthreads();
    }

    #pragma unroll
    for (int mi = 0; mi < 4; ++mi) {
        #pragma unroll
        for (int ni = 0; ni < 4; ++ni) {
            int ccol = col0 + wn * 64 + ni * 16 + l16;
            float bv = HAS_BIAS ? b2f(bias[ccol]) : 0.0f;
            #pragma unroll
            for (int i = 0; i < 4; ++i) {
                int r = row0 + wm * 64 + mi * 16 + quad * 4 + i;
                if (r < M) {
                    float v = acc[mi][ni][i] + bv;
                    if (LEAKY) v = (v >= 0.0f) ? v : 0.01f * v;
                    C[(size_t)r * N + ccol] = f2b(v);
                }
            }
        }
    }
}

// ---------- 256x256 16-wave 4-phase MFMA GEMM (r13: single barrier per phase) ----------
// Evidence: r7/r11/r12 control = 101.4+-0.6us, MfmaUtil ~23.6; r12 proved the
// lgkm-drain removal is correctness-safe (compiler waits cover reads feeding
// MFMAs) and perf-null. Cycle model: phase ~4400cyc = LDS reads ~1536 + DMA
// writes ~260 + 2 barriers x ~1300 skew. This edit removes the PRE-MFMA
// barrier (8 -> 4 barriers/iter). Ledger proof barrier#1 is superfluous:
// (WAR) STAGE in phase P targets a region last read in P-1; those reads
// retire before their MFMAs (compiler waits, r12-verified), MFMAs precede
// the end-barrier of P-1, STAGE issues after it. Same-phase stage/read
// regions disjoint by construction. (RAW) staged data covered by vmcnt(4)
// + end-barrier, unchanged. In-flight DMA during any phase targets regions
// disjoint from that phase's reads (full ledger re-walked).
// Ledger: stages P1:b1.kk1, P2:b0'.kk0, P3:b0'.kk1, P4:b1'.kk0; uniform
// vmcnt(4)/phase; prologue 6 loads vmcnt(4); tail 4/2/0/none.
template<bool LEAKY>
__global__ __launch_bounds__(1024, 4) void gemm256_kernel(
    const unsigned short* __restrict__ A,    // [MP,K] bf16 (MP = ceil256(M) readable rows)
    const unsigned short* __restrict__ Wt,   // [N,K] bf16
    const unsigned short* __restrict__ bias, // [N] bf16
    unsigned short* __restrict__ C,          // [M,N] bf16
    int M, int N, int K)                     // K multiple of 128, K>=256
{
    __shared__ __align__(16) unsigned short lds[65536];   // 128 KiB

    const int t    = threadIdx.x;
    const int lane = t & 63;
    const int wave = t >> 6;       // 0..15
    const int wm   = wave >> 2;    // 0..3  (M quarter, 64 rows)
    const int wn   = wave & 3;     // 0..3  (N quarter, 64 cols)
    const int l16  = lane & 15;
    const int q    = lane >> 4;    // 0..3

    int gx   = gridDim.x;
    int nwg  = gx * gridDim.y;
    int flat = blockIdx.y * gx + blockIdx.x;
    int qq = nwg >> 3, rr = nwg & 7;
    int xcd = flat & 7, idx = flat >> 3;
    int nf = (xcd < rr ? xcd * (qq + 1) : rr * (qq + 1) + (xcd - rr) * qq) + idx;
    const int col0 = (nf % gx) * 256;
    const int row0 = (nf / gx) * 256;

    const int srow = lane >> 2;                               // row in block
    const int scol = 8 * ((lane & 3) ^ ((lane >> 3) & 3));    // ushort col, pre-swizzled
    const int roff = l16 * 32 + 8 * (q ^ ((l16 >> 1) & 3));

    f32x4 acc[4][4] = {};

#define STAGE2(buf, kh, tile)                                                  \
    do {                                                                       \
        __builtin_amdgcn_global_load_lds(                                      \
            (const __attribute__((address_space(1))) unsigned int*)            \
                (A + (size_t)(row0 + wave * 16 + srow) * K                     \
                   + (tile) * 64 + (kh) * 32 + scol),                          \
            (__attribute__((address_space(3))) unsigned int*)                  \
                (&lds[(buf) * 32768 + wave * 1024 + (kh) * 512]),              \
            16, 0, 0);                                                         \
        __builtin_amdgcn_global_load_lds(                                      \
            (const __attribute__((address_space(1))) unsigned int*)            \
                (Wt + (size_t)(col0 + wave * 16 + srow) * K                    \
                    + (tile) * 64 + (kh) * 32 + scol),                         \
            (__attribute__((address_space(3))) unsigned int*)                  \
                (&lds[(buf) * 32768 + 16384 + wave * 1024 + (kh) * 512]),      \
            16, 0, 0);                                                         \
    } while (0)

// one phase: 8 ds_read_b128 -> issue stage -> MFMA x16 -> vmcnt -> ONE barrier.
#define PHASE(buf, kk, STAGE_STMT, WAIT_STMT)                                  \
    do {                                                                       \
        bf16x8 af_[4], bf_[4];                                                 \
        _Pragma("unroll")                                                      \
        for (int m2 = 0; m2 < 4; ++m2)                                         \
            af_[m2] = *reinterpret_cast<const bf16x8*>(                        \
                &lds[(buf) * 32768 + (wm * 4 + m2) * 1024                      \
                     + (kk) * 512 + roff]);                                    \
        _Pragma("unroll")                                                      \
        for (int n2 = 0; n2 < 4; ++n2)                                         \
            bf_[n2] = *reinterpret_cast<const bf16x8*>(                        \
                &lds[(buf) * 32768 + 16384 + (wn * 4 + n2) * 1024              \
                     + (kk) * 512 + roff]);                                    \
        STAGE_STMT;                                                            \
        __builtin_amdgcn_s_setprio(1);                                         \
        _Pragma("unroll")                                                      \
        for (int m2 = 0; m2 < 4; ++m2)                                         \
            _Pragma("unroll")                                                  \
            for (int n2 = 0; n2 < 4; ++n2)                                     \
                acc[m2][n2] = __builtin_amdgcn_mfma_f32_16x16x32_bf16(         \
                    af_[m2], bf_[n2], acc[m2][n2], 0, 0, 0);                   \
        __builtin_amdgcn_s_setprio(0);                                         \
        WAIT_STMT;                                                             \
        __builtin_amdgcn_s_barrier();                                          \
    } while (0)

    STAGE2(0, 0, 0);
    STAGE2(0, 1, 0);
    STAGE2(1, 0, 1);
    asm volatile("s_waitcnt vmcnt(4)" ::: "memory");
    __builtin_amdgcn_s_barrier();

    const int nIter = K >> 7;   // K/128, >=2 for all call sites (K=768,256)
    for (int i = 0; i < nIter - 1; ++i) {
        const int T0 = 2 * i, T1 = 2 * i + 1;
        PHASE(0, 0, STAGE2(1, 1, T1),
              asm volatile("s_waitcnt vmcnt(4)" ::: "memory"));                 // P1
        PHASE(0, 1, STAGE2(0, 0, T0 + 2),
              asm volatile("s_waitcnt vmcnt(4)" ::: "memory"));                 // P2
        PHASE(1, 0, STAGE2(0, 1, T0 + 2),
              asm volatile("s_waitcnt vmcnt(4)" ::: "memory"));                 // P3
        PHASE(1, 1, STAGE2(1, 0, T1 + 2),
              asm volatile("s_waitcnt vmcnt(4)" ::: "memory"));                 // P4
    }
    {
        const int T1 = 2 * nIter - 1;
        PHASE(0, 0, STAGE2(1, 1, T1),
              asm volatile("s_waitcnt vmcnt(4)" ::: "memory"));
        PHASE(0, 1, , asm volatile("s_waitcnt vmcnt(2)" ::: "memory"));
        PHASE(1, 0, , asm volatile("s_waitcnt vmcnt(0)" ::: "memory"));
        PHASE(1, 1, , );
    }
#undef PHASE
#undef STAGE2

    // epilogue: C/D mapping col=lane&15, row=quad*4+j  [m89/m91]
    #pragma unroll
    for (int mi = 0; mi < 4; ++mi) {
        #pragma unroll
        for (int ni = 0; ni < 4; ++ni) {
            int ccol = col0 + wn * 64 + ni * 16 + l16;
            float bv = b2f(bias[ccol]);
            #pragma unroll
            for (int j = 0; j < 4; ++j) {
                int r = row0 + wm * 64 + mi * 16 + q * 4 + j;
                if (r < M) {
                    float v = acc[mi][ni][j] + bv;
                    if (LEAKY) v = (v >= 0.0f) ? v : 0.01f * v;
                    C[(size_t)r * N + ccol] = f2b(v);
                }
            }
        }
    }
}

// ---------- CSR gather over fused layer buffer P[*,768], 2-edge unrolled (r8) ----------
__global__ __launch_bounds__(256) void gather_kernel(
    const int* __restrict__ row_ptr, const int* __restrict__ packed,
    const float* __restrict__ inv,
    const unsigned short* __restrict__ P,     // [*,768] bf16
    unsigned short* __restrict__ outp,        // [*,256] bf16
    int NN)
{
    int i    = blockIdx.x * 4 + (threadIdx.x >> 6);
    int lane = threadIdx.x & 63;
    int q    = lane >> 4;
    int l16  = lane & 15;
    if (i >= NN) return;
    float w0 = inv[i], w1 = inv[NN + i];
    float a[16] = {};
    if (q == 0) {
        const int4* rp = (const int4*)(P + (size_t)i * 768 + 512 + l16 * 16);
        union { int4 v; unsigned short s[8]; } r0u, r1u;
        r0u.v = rp[0]; r1u.v = rp[1];
        #pragma unroll
        for (int j = 0; j < 8; ++j) { a[j] = b2f(r0u.s[j]); a[8 + j] = b2f(r1u.s[j]); }
    }
    int e  = row_ptr[i] + q;
    int e1 = row_ptr[i + 1];
    for (; e + 4 < e1; e += 8) {
        int pA = packed[e];
        int pB = packed[e + 4];
        int sA = pA & 0xFFFFFF; if (sA >= NN) sA = NN - 1;
        int sB = pB & 0xFFFFFF; if (sB >= NN) sB = NN - 1;
        int rA = (pA >> 24) & 1;
        int rB = (pB >> 24) & 1;
        float wA = rA ? w1 : w0;
        float wB = rB ? w1 : w0;
        const int4* hpA = (const int4*)(P + (size_t)sA * 768 + rA * 256 + l16 * 16);
        const int4* hpB = (const int4*)(P + (size_t)sB * 768 + rB * 256 + l16 * 16);
        union { int4 v; unsigned short s8[8]; } a0, a1, b0, b1;
        a0.v = hpA[0]; a1.v = hpA[1];
        b0.v = hpB[0]; b1.v = hpB[1];
        #pragma unroll
        for (int j = 0; j < 8; ++j) {
            a[j]     += wA * b2f(a0.s8[j]);
            a[8 + j] += wA * b2f(a1.s8[j]);
        }
        #pragma unroll
        for (int j = 0; j < 8; ++j) {
            a[j]     += wB * b2f(b0.s8[j]);
            a[8 + j] += wB * b2f(b1.s8[j]);
        }
    }
    if (e < e1) {
        int p = packed[e];
        int s = p & 0xFFFFFF;
        if (s >= NN) s = NN - 1;
        int r = (p >> 24) & 1;
        float w = r ? w1 : w0;
        const int4* hp = (const int4*)(P + (size_t)s * 768 + r * 256 + l16 * 16);
        union { int4 v; unsigned short s8[8]; } h0, h1;
        h0.v = hp[0]; h1.v = hp[1];
        #pragma unroll
        for (int j = 0; j < 8; ++j) {
            a[j]     += w * b2f(h0.s8[j]);
            a[8 + j] += w * b2f(h1.s8[j]);
        }
    }
    #pragma unroll
    for (int j = 0; j < 16; ++j) {
        a[j] += __shfl_down(a[j], 32);
        a[j] += __shfl_down(a[j], 16);
    }
    if (q == 0) {
        union { int4 v; unsigned short s[8]; } o0, o1;
        #pragma unroll
        for (int j = 0; j < 8; ++j) { o0.s[j] = f2b(a[j]); o1.s[j] = f2b(a[8 + j]); }
        int4* op = (int4*)(outp + (size_t)i * 256 + l16 * 16);
        op[0] = o0.v;
        op[1] = o1.v;
    }
}

// ---------- head: softmax(h@outW + outb) over 2 classes; flag-aware store ----------
__global__ __launch_bounds__(256) void head_kernel(
    const unsigned short* __restrict__ h,
    const unsigned short* __restrict__ outW,   // [256,2] bf16 (converted)
    const unsigned short* __restrict__ outb,   // [2] bf16 (converted)
    void* __restrict__ out, int M, const int* __restrict__ flags)
{
    int row  = blockIdx.x * 4 + (threadIdx.x >> 6);
    int lane = threadIdx.x & 63;
    if (row >= M) return;
    ushort4 hv = *reinterpret_cast<const ushort4*>(h + (size_t)row * 256 + lane * 4);
    union { int4 v; unsigned short s[8]; } wu;
    wu.v = *reinterpret_cast<const int4*>(outW + lane * 8);
    float hf[4] = { b2f(hv.x), b2f(hv.y), b2f(hv.z), b2f(hv.w) };
    float s0 = 0.0f, s1 = 0.0f;
    #pragma unroll
    for (int i = 0; i < 4; ++i) {
        s0 += hf[i] * b2f(wu.s[2 * i]);
        s1 += hf[i] * b2f(wu.s[2 * i + 1]);
    }
    #pragma unroll
    for (int off2 = 32; off2 >= 1; off2 >>= 1) {
        s0 += __shfl_down(s0, off2);
        s1 += __shfl_down(s1, off2);
    }
    if (lane == 0) {
        s0 += b2f(outb[0]); s1 += b2f(outb[1]);
        float m  = fmaxf(s0, s1);
        float e0 = expf(s0 - m), e1 = expf(s1 - m);
        float is = 1.0f / (e0 + e1);
        if (flags[0]) {
            ((float*)out)[(size_t)row * 2 + 0] = e0 * is;
            ((float*)out)[(size_t)row * 2 + 1] = e1 * is;
        } else {
            ((unsigned short*)out)[(size_t)row * 2 + 0] = f2b(e0 * is);
            ((unsigned short*)out)[(size_t)row * 2 + 1] = f2b(e1 * is);
        }
    }
}

__global__ void diag_kernel(unsigned short* __restrict__ out, int n, float v) {
    int i = blockIdx.x * 256 + threadIdx.x;
    if (i < n) out[i] = f2b(v);
}

template<bool LEAKY, bool HAS_BIAS>
static void launch_gemm(const unsigned short* A, const unsigned short* Wt,
                        const unsigned short* bias, unsigned short* C,
                        int M, int N, int K, hipStream_t s) {
    int MP = (M + 127) & ~127;
    dim3 grid(N / 128, MP / 128);
    gemm_kernel<LEAKY, HAS_BIAS><<<grid, 256, 0, s>>>(A, Wt, bias, C, M, N, K);
}

template<bool LEAKY>
static void launch_gemm256(const unsigned short* A, const unsigned short* Wt,
                           const unsigned short* bias, unsigned short* C,
                           int M, int N, int K, hipStream_t s) {
    int MP = (M + 255) & ~255;
    dim3 grid(N / 256, MP / 256);
    gemm256_kernel<LEAKY><<<grid, 1024, 0, s>>>(A, Wt, bias, C, M, N, K);
}

extern "C" void kernel_launch(void* const* d_in, const int* in_sizes, int n_in,
                              void* d_out, int out_size, void* d_ws, size_t ws_size,
                              hipStream_t stream) {
    const int IN = 768, HID = 256;
    const int NN = in_sizes[0] / IN;        // 50000
    const int E  = in_sizes[3];             // 800000
    const int MPA = (NN + 255) & ~255;      // 50176 (256-tile padded rows)
    const int NB = (NN + 1023) / 1024;
    (void)n_in;

    const void* x    = d_in[0];
    const void* eidx = d_in[1];
    const void* etyp = d_in[3];
    const void* fc1W = d_in[4];
    const void* fc1b = d_in[5];
    const void* r1w  = d_in[6];
    const void* r1r  = d_in[7];
    const void* r1b  = d_in[8];
    const void* r2w  = d_in[9];
    const void* r2r  = d_in[10];
    const void* r2b  = d_in[11];
    const void* fc2W = d_in[12];
    const void* fc2b = d_in[13];
    const void* outW = d_in[14];
    const void* outb = d_in[15];

    // ---- workspace carve (~163 MB total; 187 MB proven available) ----
    char* ws = (char*)d_ws;
    size_t off = 0;
    auto carve = [&](size_t bytes) {
        char* p = ws + off; off += (bytes + 255) & ~(size_t)255; return p;
    };
    int*   flags = (int*)carve(64);
    unsigned short* fc1t  = (unsigned short*)carve((size_t)IN * IN * 2);
    unsigned short* Wcat1 = (unsigned short*)carve((size_t)IN * IN * 2);
    unsigned short* Wcat2 = (unsigned short*)carve((size_t)IN * HID * 2);
    unsigned short* fc2t  = (unsigned short*)carve((size_t)HID * HID * 2);
    unsigned short* fc1bc = (unsigned short*)carve((size_t)IN * 2);
    unsigned short* bcat1 = (unsigned short*)carve((size_t)IN * 2);
    unsigned short* bcat2 = (unsigned short*)carve((size_t)IN * 2);
    unsigned short* fc2bc = (unsigned short*)carve((size_t)HID * 2);
    unsigned short* outWc = (unsigned short*)carve((size_t)HID * 2 * 2);
    unsigned short* outbc = (unsigned short*)carve(2 * 2);
    int*   icnt    = (int*)carve((size_t)2 * NN * 4);
    float* inv     = (float*)carve((size_t)2 * NN * 4);
    int*   deg     = (int*)carve((size_t)NN * 4);
    int*   row_ptr = (int*)carve((size_t)(NN + 1) * 4);
    int*   pos     = (int*)carve((size_t)NN * 4);
    int*   bsum    = (int*)carve(256 * 4);
    int*   packed  = (int*)carve((size_t)E * 4);
    unsigned short* RA = (unsigned short*)carve((size_t)MPA * IN * 2);  // 77.1 MB
    unsigned short* RB = (unsigned short*)carve((size_t)MPA * IN * 2);  // 77.1 MB

    auto tg = [](int n) { return (n + 255) / 256; };

    if (ws_size < off) {
        float v = fminf((float)(ws_size >> 20), 300.0f) / 1000.0f;
        diag_kernel<<<tg(out_size), 256, 0, stream>>>((unsigned short*)d_out, out_size, v);
        return;
    }

    // ---- dtype detection ----
    detect_kernel<<<1, 256, 0, stream>>>(x, eidx, flags);

    // ---- fused weight prep (replaces 15 small dispatches) ----
    const int PREP_TOT = 589824 + 3 * 196608 + 3 * 65536 + 65536 + 768 * 3 + 256 + 512 + 2;
    prep_kernel<<<tg(PREP_TOT), 256, 0, stream>>>(
        fc1W, r1w, r1r, r2w, r2r, fc2W, fc1b, r1b, r2b, fc2b, outW, outb,
        fc1t, Wcat1, Wcat2, fc2t, fc1bc, bcat1, bcat2, fc2bc, outWc, outbc, flags);

    // ---- CSR build ----
    zero_kernel<<<tg(2 * NN), 256, 0, stream>>>(icnt, 2 * NN);
    count_kernel<<<tg(E), 256, 0, stream>>>(eidx, etyp, icnt, E, NN, flags);
    inv_deg_kernel<<<tg(NN), 256, 0, stream>>>(icnt, inv, deg, NN);
    blocksum_kernel<<<NB, 256, 0, stream>>>(deg, bsum, NN);
    scan_bsum_kernel<<<1, 64, 0, stream>>>(bsum, NB);
    scan_phase3<<<NB, 256, 0, stream>>>(deg, bsum, row_ptr, pos, NN);
    fill_kernel<<<tg(E), 256, 0, stream>>>(eidx, etyp, pos, packed, E, NN, flags);

    // ---- x -> bf16 (RA) ----
    convx_kernel<<<tg(NN * IN / 8), 256, 0, stream>>>(x, RA, NN * IN / 8, flags);

    // ---- fc1 + leakyrelu: XB(RA) -> H1(RB)  [256sq 16-wave, 1-barrier phases] ----
    launch_gemm256<true>(RA, fc1t, fc1bc, RB, NN, IN, IN, stream);

    // ---- layer 1 (fused): H1(RB) @ Wcat1 -> P1(RA) ; gather -> ACC1(RB head) ----
    launch_gemm256<false>(RB, Wcat1, bcat1, RA, NN, IN, IN, stream);
    gather_kernel<<<(NN + 3) / 4, 256, 0, stream>>>(row_ptr, packed, inv, RA, RB, NN);

    // ---- layer 2 (fused): ACC1(RB) @ Wcat2 -> P2(RA) ; gather -> ACC2(RB head) ----
    launch_gemm256<false>(RB, Wcat2, bcat2, RA, NN, IN, HID, stream);
    gather_kernel<<<(NN + 3) / 4, 256, 0, stream>>>(row_ptr, packed, inv, RA, RB, NN);

    // ---- fc2 + leakyrelu: ACC2(RB) -> H4(RA head) ; softmax head (128-tile: N=256) ----
    launch_gemm<true, true>(RB, fc2t, fc2bc, RA, NN, HID, HID, stream);
    head_kernel<<<(NN + 3) / 4, 256, 0, stream>>>(RA, outWc, outbc, d_out, NN, flags);
}